// Round 1
// baseline (873.681 us; speedup 1.0000x reference)
//
#include <hip/hip_runtime.h>

#define BATCH 1024
#define DIM   512
#define MODES 256

// ---------------------------------------------------------------------------
// Kernel A: scores = softmax(x @ W^T + b) over the mode axis.
// One block (256 threads) handles 4 batch rows. x rows staged in LDS.
// Thread m computes the dot product for mode m against all 4 rows (W row
// loads are float4; W is 512 KB => L2-resident after first touch).
// Then: logits tile -> LDS, each of the 4 waves softmaxes one row via
// 64-lane shuffle reductions.
// ---------------------------------------------------------------------------
__global__ __launch_bounds__(256) void scores_kernel(
    const float* __restrict__ x, const float* __restrict__ W,
    const float* __restrict__ bias, float* __restrict__ scores) {
  __shared__ float xs[4 * DIM];    // 8 KB: 4 rows of x
  __shared__ float lg[4 * MODES];  // 4 KB: logits tile [row][mode]

  const int tid = threadIdx.x;
  const int b0  = blockIdx.x * 4;

  // stage 4 x rows into LDS (coalesced float4)
  const float4* xg  = (const float4*)(x + (size_t)b0 * DIM);
  float4*       xs4 = (float4*)xs;
  for (int i = tid; i < 4 * DIM / 4; i += 256) xs4[i] = xg[i];
  __syncthreads();

  const int m = tid;  // one mode per thread
  const float4* Wrow = (const float4*)(W + (size_t)m * DIM);
  const float bm = bias[m];
  float a0 = bm, a1 = bm, a2 = bm, a3 = bm;

  #pragma unroll 4
  for (int k4 = 0; k4 < DIM / 4; ++k4) {
    const float4 w  = Wrow[k4];
    const float4 x0 = xs4[k4];
    const float4 x1 = xs4[1 * (DIM / 4) + k4];
    const float4 x2 = xs4[2 * (DIM / 4) + k4];
    const float4 x3 = xs4[3 * (DIM / 4) + k4];
    a0 = fmaf(w.x, x0.x, fmaf(w.y, x0.y, fmaf(w.z, x0.z, fmaf(w.w, x0.w, a0))));
    a1 = fmaf(w.x, x1.x, fmaf(w.y, x1.y, fmaf(w.z, x1.z, fmaf(w.w, x1.w, a1))));
    a2 = fmaf(w.x, x2.x, fmaf(w.y, x2.y, fmaf(w.z, x2.z, fmaf(w.w, x2.w, a2))));
    a3 = fmaf(w.x, x3.x, fmaf(w.y, x3.y, fmaf(w.z, x3.z, fmaf(w.w, x3.w, a3))));
  }

  lg[0 * MODES + m] = a0;
  lg[1 * MODES + m] = a1;
  lg[2 * MODES + m] = a2;
  lg[3 * MODES + m] = a3;
  __syncthreads();

  // wave w softmaxes row w (256 logits, 4 per lane)
  const int wv   = tid >> 6;
  const int lane = tid & 63;
  const float* row = lg + wv * MODES;
  float v0 = row[lane];
  float v1 = row[lane + 64];
  float v2 = row[lane + 128];
  float v3 = row[lane + 192];

  float mx = fmaxf(fmaxf(v0, v1), fmaxf(v2, v3));
  #pragma unroll
  for (int off = 32; off; off >>= 1) mx = fmaxf(mx, __shfl_xor(mx, off, 64));

  const float e0 = expf(v0 - mx);
  const float e1 = expf(v1 - mx);
  const float e2 = expf(v2 - mx);
  const float e3 = expf(v3 - mx);
  float s = e0 + e1 + e2 + e3;
  #pragma unroll
  for (int off = 32; off; off >>= 1) s += __shfl_xor(s, off, 64);

  const float inv = 1.0f / s;
  float* out = scores + (size_t)(b0 + wv) * MODES;
  out[lane]       = e0 * inv;
  out[lane + 64]  = e1 * inv;
  out[lane + 128] = e2 * inv;
  out[lane + 192] = e3 * inv;
}

// ---------------------------------------------------------------------------
// Kernel B: the big memory-bound pass.
//   mem_new[m,b,d] = beta_m * mem[m,b,d] + x[b,d] - (mem[m,b,d] > 1)
//   mixed[b,d]     = sum_m (mem_new[m,b,d] > 1) * scores[b,m]
// One thread per float4 of (b,d); loops over all 256 modes.
// mem/mem_new accesses are fully coalesced 16 B/lane. scores[b][m] is
// wave-uniform (64 lanes span half a D-row => same b).
// Exact-rounding intrinsics (__fmul_rn etc.) forbid FMA contraction so
// mem_new matches the numpy reference bit-for-bit => the >1 spike
// comparisons match exactly.
// ---------------------------------------------------------------------------
__global__ __launch_bounds__(256) void fused_kernel(
    const float* __restrict__ x, const float* __restrict__ mem,
    const float* __restrict__ scores, float* __restrict__ mixed,
    float* __restrict__ mem_new) {
  const int idx4 = blockIdx.x * 256 + threadIdx.x;  // 0 .. B*D/4-1
  const int b = idx4 >> 7;                          // D/4 = 128 float4 per row

  const float4* mem4  = (const float4*)mem;
  float4*       memn4 = (float4*)mem_new;
  const float4  xv    = ((const float4*)x)[idx4];
  const float4* srow4 = (const float4*)(scores + (size_t)b * MODES);

  float4 acc = make_float4(0.f, 0.f, 0.f, 0.f);

  #pragma unroll 2
  for (int m4 = 0; m4 < MODES / 4; ++m4) {
    const float4 sv = srow4[m4];
    #pragma unroll
    for (int j = 0; j < 4; ++j) {
      const int m = m4 * 4 + j;
      const float beta = (float)m / 257.0f;  // matches np: arange/257 in fp32
      const size_t off = (size_t)m * (BATCH * DIM / 4) + idx4;
      const float4 mv = mem4[off];
      const float sj = (j == 0) ? sv.x : (j == 1) ? sv.y : (j == 2) ? sv.z : sv.w;

      float4 nv;
      nv.x = __fsub_rn(__fadd_rn(__fmul_rn(beta, mv.x), xv.x), (mv.x > 1.0f) ? 1.0f : 0.0f);
      nv.y = __fsub_rn(__fadd_rn(__fmul_rn(beta, mv.y), xv.y), (mv.y > 1.0f) ? 1.0f : 0.0f);
      nv.z = __fsub_rn(__fadd_rn(__fmul_rn(beta, mv.z), xv.z), (mv.z > 1.0f) ? 1.0f : 0.0f);
      nv.w = __fsub_rn(__fadd_rn(__fmul_rn(beta, mv.w), xv.w), (mv.w > 1.0f) ? 1.0f : 0.0f);
      memn4[off] = nv;

      acc.x += (nv.x > 1.0f) ? sj : 0.0f;
      acc.y += (nv.y > 1.0f) ? sj : 0.0f;
      acc.z += (nv.z > 1.0f) ? sj : 0.0f;
      acc.w += (nv.w > 1.0f) ? sj : 0.0f;
    }
  }

  ((float4*)mixed)[idx4] = acc;
}

extern "C" void kernel_launch(void* const* d_in, const int* in_sizes, int n_in,
                              void* d_out, int out_size, void* d_ws, size_t ws_size,
                              hipStream_t stream) {
  const float* x   = (const float*)d_in[0];  // [B, D]
  const float* mem = (const float*)d_in[1];  // [M, B, D]
  const float* W   = (const float*)d_in[2];  // [M, D]
  const float* b   = (const float*)d_in[3];  // [M]

  float* out     = (float*)d_out;
  float* mixed   = out;                                  // [B, D]   = 524288
  float* mem_new = out + (size_t)BATCH * DIM;            // [M, B, D] = 134217728
  float* scores  = mem_new + (size_t)MODES * BATCH * DIM;  // [B, M] = 262144

  scores_kernel<<<BATCH / 4, 256, 0, stream>>>(x, W, b, scores);

  const int n4 = BATCH * DIM / 4;  // 131072 float4 positions
  fused_kernel<<<n4 / 256, 256, 0, stream>>>(x, mem, scores, mixed, mem_new);
}